// Round 19
// baseline (1220.897 us; speedup 1.0000x reference)
//
#include <hip/hip_runtime.h>
#include <math.h>

// AddrNet eval forward: B=524288, D_MODEL=128, HID=16, N_BINS=256, DEPTH=8.
// Round 19: R18 (PASSING, 618us) with an index-STUFFED screen tracker:
//  - wave-uniform C = 8*hmax_wave+1 added to bias (biasC table in the spare
//    stage dwords) -> all screen values positive -> IEEE order == bit order.
//  - bin index stuffed into low 8 mantissa bits (v_bfi); top-3 tracking is
//    pure fmax/fmed3/fmin (5 ops/value, no cmp/cndmask); merge is 3-shfl +
//    max/min net; index recovered as bits&0xFF.
//  - EPS2 = 4e-3*hmax_wave + 2e-4 (covers MFMA 1.3e-4*hmax + 2x stuffing
//    4.9e-4*hmax with 3.2x safety). Certified resolution unchanged in kind:
//    unique -> take; 2 within EPS2 -> exact no-FMA duel (first-index ties);
//    3 within -> full exact no-FMA argmax (R4 semantics).
//  - output bins kept in regs, written once as 2x int4 (kills ~33MB of HBM
//    write amplification from scattered 4B stores).
// h-trajectory (input, embed, MLP, np-Cephes exp, mul-silu): bit-exact no-FMA
// R4 contract, unchanged.

constexpr int BATCH  = 524288;
constexpr int DM     = 128;
constexpr int H      = 16;
constexpr int NB     = 256;
constexpr int DEPTHN = 8;

constexpr int BLOCK = 256;
constexpr int STG   = 20;   // 16 dwords split-h + 4 dwords biasC per lane

typedef float v2f    __attribute__((ext_vector_type(2)));
typedef float f32x4  __attribute__((ext_vector_type(4)));
typedef int   i32x4  __attribute__((ext_vector_type(4)));
typedef short bf16x8 __attribute__((ext_vector_type(8)));

__device__ __forceinline__ unsigned bf16_rne(float f) {
    unsigned u = __builtin_bit_cast(unsigned, f);
    return (u + 0x7fffu + ((u >> 16) & 1u)) >> 16;
}
__device__ __forceinline__ float bf16_to_f(unsigned b) {
    return __builtin_bit_cast(float, b << 16);
}

__device__ __forceinline__ float np_expf(float x) {
    // numpy SIMD f32 exp replica (Cephes). Verified R4 contract — do not touch.
    const float LOG2E = 1.442695040888963407f;
    const float C1    = 0.693359375f;
    const float C2    = -2.12194440e-4f;
    float q = rintf(x * LOG2E);
    float r = __builtin_fmaf(q, -C1, x);
    r = __builtin_fmaf(q, -C2, r);
    float p = 1.9875691500E-4f;
    p = __builtin_fmaf(p, r, 1.3981999507E-3f);
    p = __builtin_fmaf(p, r, 8.3334519073E-3f);
    p = __builtin_fmaf(p, r, 4.1665795894E-2f);
    p = __builtin_fmaf(p, r, 1.6666665459E-1f);
    p = __builtin_fmaf(p, r, 5.0000001201E-1f);
    p = __builtin_fmaf(p, r * r, r);
    p = p + 1.0f;
    if (x > 88.72283935546875f)      return INFINITY;
    if (x < -103.97208404541015625f) return 0.0f;
    return ldexpf(p, (int)q);
}

// ---- prep: exact-path weight layouts in d_ws (same as R14-R18).
__global__ void addrnet_prep_kernel(const float* __restrict__ W_out,
                                    const float* __restrict__ W_mlp,
                                    float* __restrict__ ws) {
    int t = threadIdx.x;
    for (int i = t; i < NB * H; i += 256) {
        int p = i >> 5, r = i & 31;
        int k = r >> 1, hh = r & 1;
        ws[i] = W_out[k * NB + (2 * p + hh)];
    }
    {
        int ii = t >> 4, k = t & 15;
        ws[NB * H + ii * H + k] = W_mlp[k * H + ii];
    }
}

__global__ __launch_bounds__(BLOCK, 2) void addrnet_r19_kernel(
    const float* __restrict__ x,      // [B,128]
    const float* __restrict__ W_in,   // [128,16]
    const float* __restrict__ b_in,   // [16]
    const float* __restrict__ embed,  // [256,16]
    const float* __restrict__ b_mlp,  // [16]
    const float* __restrict__ b_out,  // [256]
    const float* __restrict__ W_out,  // [16,256] (A-frag build)
    const float* __restrict__ ws,     // exact-path layouts
    int* __restrict__ out)            // [B,8] int32
{
#pragma clang fp contract(off)
    __shared__ __align__(16) int   sA[16][64][4];       // 16 KB  W-frags (v0)
    __shared__ __align__(16) int   sStage[4][64 * STG]; // 20 KB  h + biasC
    __shared__ __align__(16) float sBias[NB];           //  1 KB

    const int tid = threadIdx.x;
    const int ln  = tid & 63;
    const int wid = tid >> 6;

    // ---- build A-fragments (variant0), same as R16/R18 (verified) ----
    for (int slot = tid; slot < 16 * 64; slot += BLOCK) {
        int bt = slot >> 6, l = slot & 63;
        int m  = 16 * bt + (l & 15);
        int k0 = (l >> 4) * 8;
        for (int j = 0; j < 4; ++j) {
            unsigned e2[2];
            for (int e = 0; e < 2; ++e) {
                int k  = k0 + 2 * j + e;
                int kk = k & 15;
                float w = W_out[kk * NB + m];
                unsigned whi = bf16_rne(w);
                unsigned wlo = bf16_rne(w - bf16_to_f(whi));
                e2[e] = (k < 16) ? whi : wlo;
            }
            sA[bt][l][j] = (int)(e2[0] | (e2[1] << 16));
        }
    }
    if (tid < NB) sBias[tid] = b_out[tid];
    __syncthreads();

    const float* WM = ws + NB * H;                       // WmlpT[i][k]
    const v2f*   WP = reinterpret_cast<const v2f*>(ws);  // exact pair layout

    const int row = blockIdx.x * BLOCK + tid;

    // ---- h = x @ W_in + b_in : EXACT no-FMA, k ascending, bias after ----
    float h[H];
#pragma unroll
    for (int j = 0; j < H; ++j) h[j] = 0.0f;
    const float4* xr = reinterpret_cast<const float4*>(x + (size_t)row * DM);
    for (int k4 = 0; k4 < DM / 4; ++k4) {
        float4 v = xr[k4];
        const float* w0 = &W_in[(k4 * 4 + 0) * H];
        const float* w1 = &W_in[(k4 * 4 + 1) * H];
        const float* w2 = &W_in[(k4 * 4 + 2) * H];
        const float* w3 = &W_in[(k4 * 4 + 3) * H];
#pragma unroll
        for (int j = 0; j < H; ++j) {
            float a = h[j];
            a = a + v.x * w0[j];
            a = a + v.y * w1[j];
            a = a + v.z * w2[j];
            a = a + v.w * w3[j];
            h[j] = a;
        }
    }
#pragma unroll
    for (int j = 0; j < H; ++j) h[j] = h[j] + b_in[j];

    int* stme = &sStage[wid][ln * STG];
    float* stmef = reinterpret_cast<float*>(stme);
    const float* swf = reinterpret_cast<const float*>(&sStage[wid][0]);
    const int binbase = (ln >> 4) * 4;
    const int idq0 = binbase, idq1 = binbase + 1, idq2 = binbase + 2, idq3 = binbase + 3;

    int bins_[DEPTHN];

    for (int d = 0; d < DEPTHN; ++d) {
        // per-lane hmax (tree)
        float m01 = fmaxf(fabsf(h[0]), fabsf(h[1]));
        float m23 = fmaxf(fabsf(h[2]), fabsf(h[3]));
        float m45 = fmaxf(fabsf(h[4]), fabsf(h[5]));
        float m67 = fmaxf(fabsf(h[6]), fabsf(h[7]));
        float m89 = fmaxf(fabsf(h[8]), fabsf(h[9]));
        float mab = fmaxf(fabsf(h[10]), fabsf(h[11]));
        float mcd = fmaxf(fabsf(h[12]), fabsf(h[13]));
        float mef = fmaxf(fabsf(h[14]), fabsf(h[15]));
        float hmax = fmaxf(fmaxf(fmaxf(m01, m23), fmaxf(m45, m67)),
                           fmaxf(fmaxf(m89, mab), fmaxf(mcd, mef)));
        // wave-max hmax
        float hw = hmax;
#pragma unroll
        for (int s = 1; s < 64; s <<= 1) hw = fmaxf(hw, __shfl_xor(hw, s));
        const float CSH  = 8.0f * hw + 1.0f;
        const float EPS2 = 4e-3f * hw + 2e-4f;

        // ---- bf16 2-term split; dwords [hi pairs(8) | lo pairs(8)] ----
        int dw[16];
#pragma unroll
        for (int i = 0; i < 8; ++i) {
            unsigned a  = bf16_rne(h[2 * i]);
            unsigned b  = bf16_rne(h[2 * i + 1]);
            unsigned la = bf16_rne(h[2 * i]     - bf16_to_f(a));
            unsigned lb = bf16_rne(h[2 * i + 1] - bf16_to_f(b));
            dw[i]     = (int)(a  | (b  << 16));
            dw[8 + i] = (int)(la | (lb << 16));
        }
        {
            i32x4 s0 = {dw[0], dw[1], dw[2], dw[3]};
            i32x4 s1 = {dw[4], dw[5], dw[6], dw[7]};
            i32x4 s2 = {dw[8], dw[9], dw[10], dw[11]};
            i32x4 s3 = {dw[12], dw[13], dw[14], dw[15]};
            *reinterpret_cast<i32x4*>(&stme[0])  = s0;
            *reinterpret_cast<i32x4*>(&stme[4])  = s1;
            *reinterpret_cast<i32x4*>(&stme[8])  = s2;
            *reinterpret_cast<i32x4*>(&stme[12]) = s3;
        }
        // ---- biasC table: lane ln owns bins 4ln..4ln+3 -> stage slots 16..19
        {
            const float4 bb = *reinterpret_cast<const float4*>(&sBias[ln * 4]);
            float4 bc = {bb.x + CSH, bb.y + CSH, bb.z + CSH, bb.w + CSH};
            *reinterpret_cast<float4*>(&stmef[16]) = bc;
        }

        // ---- B-frags (h): rowgroup g, lane ln: row (ln&15)+16g, kgrp ln>>4 ----
        bf16x8 bfr[4];
#pragma unroll
        for (int g = 0; g < 4; ++g) {
            const i32x4* p = reinterpret_cast<const i32x4*>(
                &sStage[wid][((ln & 15) + 16 * g) * STG + (ln >> 4) * 4]);
            bfr[g] = __builtin_bit_cast(bf16x8, *p);
        }

        // running stuffed top-3 per rowgroup (values carry bin idx in low byte)
        float p10 = -INFINITY, p20 = -INFINITY, p30 = -INFINITY;
        float p11 = -INFINITY, p21 = -INFINITY, p31 = -INFINITY;
        float p12 = -INFINITY, p22 = -INFINITY, p32 = -INFINITY;
        float p13 = -INFINITY, p23 = -INFINITY, p33 = -INFINITY;

#define SINS(M1, M2, M3, V, IB)                                            \
        {                                                                  \
            unsigned sb_ = (__builtin_bit_cast(unsigned, (V)) &            \
                            0xFFFFFF00u) | (unsigned)(IB);                 \
            float sv_ = __builtin_bit_cast(float, sb_);                    \
            M3 = fmaxf(M3, fminf(M2, sv_));                                \
            M2 = __builtin_amdgcn_fmed3f(M1, M2, sv_);                     \
            M1 = fmaxf(M1, sv_);                                           \
        }

        for (int bt = 0; bt < 16; ++bt) {
            i32x4 a0i = *reinterpret_cast<const i32x4*>(&sA[bt][ln][0]);
            i32x4 a1i = *reinterpret_cast<const i32x4*>(&sA[bt][ln ^ 32][0]);
            bf16x8 a0 = __builtin_bit_cast(bf16x8, a0i);
            bf16x8 a1 = __builtin_bit_cast(bf16x8, a1i);
            f32x4 biasC4 = *reinterpret_cast<const f32x4*>(
                &swf[(4 * bt + (binbase >> 2)) * STG + 16]);
            const int ib0 = (bt << 4) | idq0;
            const int ib1 = (bt << 4) | idq1;
            const int ib2 = (bt << 4) | idq2;
            const int ib3 = (bt << 4) | idq3;
#pragma unroll
            for (int g = 0; g < 4; ++g) {
                f32x4 acc = biasC4;
                acc = __builtin_amdgcn_mfma_f32_16x16x32_bf16(a0, bfr[g], acc, 0, 0, 0);
                acc = __builtin_amdgcn_mfma_f32_16x16x32_bf16(a1, bfr[g], acc, 0, 0, 0);
                if (g == 0) {
                    SINS(p10, p20, p30, acc[0], ib0);
                    SINS(p10, p20, p30, acc[1], ib1);
                    SINS(p10, p20, p30, acc[2], ib2);
                    SINS(p10, p20, p30, acc[3], ib3);
                } else if (g == 1) {
                    SINS(p11, p21, p31, acc[0], ib0);
                    SINS(p11, p21, p31, acc[1], ib1);
                    SINS(p11, p21, p31, acc[2], ib2);
                    SINS(p11, p21, p31, acc[3], ib3);
                } else if (g == 2) {
                    SINS(p12, p22, p32, acc[0], ib0);
                    SINS(p12, p22, p32, acc[1], ib1);
                    SINS(p12, p22, p32, acc[2], ib2);
                    SINS(p12, p22, p32, acc[3], ib3);
                } else {
                    SINS(p13, p23, p33, acc[0], ib0);
                    SINS(p13, p23, p33, acc[1], ib1);
                    SINS(p13, p23, p33, acc[2], ib2);
                    SINS(p13, p23, p33, acc[3], ib3);
                }
            }
        }
#undef SINS

        // ---- merge across the 4 bin-holder lanes (xor16, xor32); keep own ----
        float kmx = -INFINITY, ksec = -INFINITY, kt3 = -INFINITY;
#define MERGE_KEEP(M1, M2, M3, G)                                          \
        {                                                                  \
            float m1_ = M1, m2_ = M2, m3_ = M3;                            \
            _Pragma("unroll")                                              \
            for (int s = 16; s <= 32; s <<= 1) {                           \
                float q1 = __shfl_xor(m1_, s);                             \
                float q2 = __shfl_xor(m2_, s);                             \
                float q3 = __shfl_xor(m3_, s);                             \
                float nm1 = fmaxf(m1_, q1);                                \
                float nm2 = fmaxf(fminf(m1_, q1), fmaxf(m2_, q2));         \
                float nm3 = fmaxf(fmaxf(fminf(m2_, q1), fminf(m1_, q2)),   \
                                  fmaxf(m3_, q3));                         \
                m1_ = nm1; m2_ = nm2; m3_ = nm3;                           \
            }                                                              \
            bool own = ((ln >> 4) == (G));                                 \
            kmx = own ? m1_ : kmx;                                         \
            ksec = own ? m2_ : ksec;                                       \
            kt3 = own ? m3_ : kt3;                                         \
        }
        MERGE_KEEP(p10, p20, p30, 0)
        MERGE_KEEP(p11, p21, p31, 1)
        MERGE_KEEP(p12, p22, p32, 2)
        MERGE_KEEP(p13, p23, p33, 3)
#undef MERGE_KEEP

        int kgb = (int)(__builtin_bit_cast(unsigned, kmx) & 0xFFu);
        int ki2 = (int)(__builtin_bit_cast(unsigned, ksec) & 0xFFu);

        // ---- certified resolution ----
        int bi;
        if (kmx - kt3 <= EPS2) {
            // full exact no-FMA argmax (rare)
            float bb2 = -INFINITY;
            int bj = 0;
            for (int p = 0; p < NB / 2; ++p) {
                const v2f* wr = &WP[p * H];
                float a0 = 0.0f, a1 = 0.0f;
#pragma unroll
                for (int k = 0; k < H; ++k) {
                    v2f w = wr[k];
                    a0 = a0 + h[k] * w.x;
                    a1 = a1 + h[k] * w.y;
                }
                a0 = a0 + b_out[2 * p];
                a1 = a1 + b_out[2 * p + 1];
                if (a0 > bb2) { bb2 = a0; bj = 2 * p; }
                if (a1 > bb2) { bb2 = a1; bj = 2 * p + 1; }
            }
            bi = bj;
        } else if (kmx - ksec <= EPS2) {
            // exact 2-bin duel, first-index ties
            int lo  = kgb < ki2 ? kgb : ki2;
            int hi2 = kgb < ki2 ? ki2 : kgb;
            float El = 0.0f, Eh = 0.0f;
            {
                const float* wr = ws + (lo >> 1) * 32 + (lo & 1);
#pragma unroll
                for (int k = 0; k < H; ++k) El = El + h[k] * wr[2 * k];
                El = El + b_out[lo];
            }
            {
                const float* wr = ws + (hi2 >> 1) * 32 + (hi2 & 1);
#pragma unroll
                for (int k = 0; k < H; ++k) Eh = Eh + h[k] * wr[2 * k];
                Eh = Eh + b_out[hi2];
            }
            bi = (Eh > El) ? hi2 : lo;
        } else {
            bi = kgb;
        }
        bins_[d] = bi;

        // ---- h = h + embed[bi] : EXACT (global gather, cached) ----
        {
            const float4* e = reinterpret_cast<const float4*>(embed + bi * H);
#pragma unroll
            for (int q4 = 0; q4 < 4; ++q4) {
                float4 ev = e[q4];
                h[q4 * 4 + 0] = h[q4 * 4 + 0] + ev.x;
                h[q4 * 4 + 1] = h[q4 * 4 + 1] + ev.y;
                h[q4 * 4 + 2] = h[q4 * 4 + 2] + ev.z;
                h[q4 * 4 + 3] = h[q4 * 4 + 3] + ev.w;
            }
        }

        // ---- z = h @ W_mlp + b_mlp ; silu : EXACT no-FMA + np-exp ----
        float hn[H];
#pragma unroll
        for (int i = 0; i < H; ++i) {
            const float* wr = &WM[i * H];
            float acc = 0.0f;
#pragma unroll
            for (int k = 0; k < H; ++k) acc = acc + h[k] * wr[k];
            acc = acc + b_mlp[i];
            float e = np_expf(-acc);
            float s = 1.0f / (1.0f + e);
            hn[i] = acc * s;
        }
#pragma unroll
        for (int i = 0; i < H; ++i) h[i] = hn[i];
    }

    // ---- write all bins once: 2x int4, coalesced ----
    int* o = out + (size_t)row * DEPTHN;
    *reinterpret_cast<int4*>(o)     = make_int4(bins_[0], bins_[1], bins_[2], bins_[3]);
    *reinterpret_cast<int4*>(o + 4) = make_int4(bins_[4], bins_[5], bins_[6], bins_[7]);
}

extern "C" void kernel_launch(void* const* d_in, const int* in_sizes, int n_in,
                              void* d_out, int out_size, void* d_ws, size_t ws_size,
                              hipStream_t stream) {
    const float* x     = (const float*)d_in[0];
    const float* W_in  = (const float*)d_in[1];
    const float* b_in  = (const float*)d_in[2];
    const float* embed = (const float*)d_in[3];
    const float* W_mlp = (const float*)d_in[4];
    const float* b_mlp = (const float*)d_in[5];
    const float* W_out = (const float*)d_in[6];
    const float* b_out = (const float*)d_in[7];
    int* out  = (int*)d_out;
    float* ws = (float*)d_ws;          // needs (4096+256)*4 = 17.4 KB

    addrnet_prep_kernel<<<1, 256, 0, stream>>>(W_out, W_mlp, ws);

    dim3 grid(BATCH / BLOCK);          // 2048 blocks, 8192 waves
    dim3 block(BLOCK);
    addrnet_r19_kernel<<<grid, block, 0, stream>>>(x, W_in, b_in, embed,
                                                   b_mlp, b_out, W_out, ws, out);
}

// Round 20
// 1220.164 us; speedup vs baseline: 1.0006x; 1.0006x over previous
//
#include <hip/hip_runtime.h>
#include <math.h>

// AddrNet eval forward: B=524288, D_MODEL=128, HID=16, N_BINS=256, DEPTH=8.
// Round 20: R18 base (PASSING 618us) + SHIFT-FREE stuffed tracker:
//  - bin idx stuffed into low 8 mantissa bits at the NATURAL logit scale
//    (no positivity shift -> stuffing noise ~1.2e-4*hmax, not 2e-3*hw;
//    R19's regression was the shift's ulp inflation exploding fallbacks).
//  - top-3 tracking: 5 ops/value (bfi + fmax/fmed3/fmin); merge: 3 shfl +
//    max/min net (validated absmax-0 in R19); idx = bits&0xFF (sign-safe).
//  - EPS_duel = 6e-4*hmax+1e-5 (R18's proven rate); EPS_full = 1.2e-3*hmax
//    +2e-5 — looser so any stuffed sec<->t3 index swap (needs |sec-t3| <=
//    4.8e-4*hmax) forces the full-exact branch, keeping the duel sound.
//  - bins kept in regs, stored once as 2x int4 (R19-proven WRITE fix).
// h-trajectory (input, embed, MLP, np-Cephes exp, mul-silu): bit-exact
// no-FMA R4 contract, unchanged. Screen MFMA path unchanged from R16/R18.

constexpr int BATCH  = 524288;
constexpr int DM     = 128;
constexpr int H      = 16;
constexpr int NB     = 256;
constexpr int DEPTHN = 8;

constexpr int BLOCK = 256;
constexpr int STG   = 20;          // stage stride in dwords (>=16), 16B-aligned

typedef float v2f    __attribute__((ext_vector_type(2)));
typedef float f32x4  __attribute__((ext_vector_type(4)));
typedef int   i32x4  __attribute__((ext_vector_type(4)));
typedef short bf16x8 __attribute__((ext_vector_type(8)));

__device__ __forceinline__ unsigned bf16_rne(float f) {
    unsigned u = __builtin_bit_cast(unsigned, f);
    return (u + 0x7fffu + ((u >> 16) & 1u)) >> 16;
}
__device__ __forceinline__ float bf16_to_f(unsigned b) {
    return __builtin_bit_cast(float, b << 16);
}

__device__ __forceinline__ float np_expf(float x) {
    // numpy SIMD f32 exp replica (Cephes). Verified R4 contract — do not touch.
    const float LOG2E = 1.442695040888963407f;
    const float C1    = 0.693359375f;
    const float C2    = -2.12194440e-4f;
    float q = rintf(x * LOG2E);
    float r = __builtin_fmaf(q, -C1, x);
    r = __builtin_fmaf(q, -C2, r);
    float p = 1.9875691500E-4f;
    p = __builtin_fmaf(p, r, 1.3981999507E-3f);
    p = __builtin_fmaf(p, r, 8.3334519073E-3f);
    p = __builtin_fmaf(p, r, 4.1665795894E-2f);
    p = __builtin_fmaf(p, r, 1.6666665459E-1f);
    p = __builtin_fmaf(p, r, 5.0000001201E-1f);
    p = __builtin_fmaf(p, r * r, r);
    p = p + 1.0f;
    if (x > 88.72283935546875f)      return INFINITY;
    if (x < -103.97208404541015625f) return 0.0f;
    return ldexpf(p, (int)q);
}

// ---- prep: exact-path weight layouts in d_ws (same as R14-R18).
//   ws[p*32 + k*2 + hh] = W_out[k][2p+hh]   p in [0,128)
//   ws[4096 + i*16 + k] = W_mlp[k][i]
__global__ void addrnet_prep_kernel(const float* __restrict__ W_out,
                                    const float* __restrict__ W_mlp,
                                    float* __restrict__ ws) {
    int t = threadIdx.x;
    for (int i = t; i < NB * H; i += 256) {
        int p = i >> 5, r = i & 31;
        int k = r >> 1, hh = r & 1;
        ws[i] = W_out[k * NB + (2 * p + hh)];
    }
    {
        int ii = t >> 4, k = t & 15;
        ws[NB * H + ii * H + k] = W_mlp[k * H + ii];
    }
}

__global__ __launch_bounds__(BLOCK, 2) void addrnet_r20_kernel(
    const float* __restrict__ x,      // [B,128]
    const float* __restrict__ W_in,   // [128,16]
    const float* __restrict__ b_in,   // [16]
    const float* __restrict__ embed,  // [256,16]
    const float* __restrict__ b_mlp,  // [16]
    const float* __restrict__ b_out,  // [256]
    const float* __restrict__ W_out,  // [16,256] (A-frag build)
    const float* __restrict__ ws,     // exact-path layouts
    int* __restrict__ out)            // [B,8] int32
{
#pragma clang fp contract(off)
    __shared__ __align__(16) int   sA[16][64][4];       // 16 KB  W-frags (v0)
    __shared__ __align__(16) int   sStage[4][64 * STG]; // 20 KB  h exchange
    __shared__ __align__(16) float sBias[NB];           //  1 KB

    const int tid = threadIdx.x;
    const int ln  = tid & 63;
    const int wid = tid >> 6;

    // ---- build A-fragments (variant0), verified in R15-R18 ----
    for (int slot = tid; slot < 16 * 64; slot += BLOCK) {
        int bt = slot >> 6, l = slot & 63;
        int m  = 16 * bt + (l & 15);
        int k0 = (l >> 4) * 8;
        for (int j = 0; j < 4; ++j) {
            unsigned e2[2];
            for (int e = 0; e < 2; ++e) {
                int k  = k0 + 2 * j + e;
                int kk = k & 15;
                float w = W_out[kk * NB + m];
                unsigned whi = bf16_rne(w);
                unsigned wlo = bf16_rne(w - bf16_to_f(whi));
                e2[e] = (k < 16) ? whi : wlo;
            }
            sA[bt][l][j] = (int)(e2[0] | (e2[1] << 16));
        }
    }
    if (tid < NB) sBias[tid] = b_out[tid];
    __syncthreads();

    const float* WM = ws + NB * H;                       // WmlpT[i][k]
    const v2f*   WP = reinterpret_cast<const v2f*>(ws);  // exact pair layout

    const int row = blockIdx.x * BLOCK + tid;

    // ---- h = x @ W_in + b_in : EXACT no-FMA, k ascending, bias after ----
    float h[H];
#pragma unroll
    for (int j = 0; j < H; ++j) h[j] = 0.0f;
    const float4* xr = reinterpret_cast<const float4*>(x + (size_t)row * DM);
    for (int k4 = 0; k4 < DM / 4; ++k4) {
        float4 v = xr[k4];
        const float* w0 = &W_in[(k4 * 4 + 0) * H];
        const float* w1 = &W_in[(k4 * 4 + 1) * H];
        const float* w2 = &W_in[(k4 * 4 + 2) * H];
        const float* w3 = &W_in[(k4 * 4 + 3) * H];
#pragma unroll
        for (int j = 0; j < H; ++j) {
            float a = h[j];
            a = a + v.x * w0[j];
            a = a + v.y * w1[j];
            a = a + v.z * w2[j];
            a = a + v.w * w3[j];
            h[j] = a;
        }
    }
#pragma unroll
    for (int j = 0; j < H; ++j) h[j] = h[j] + b_in[j];

    int* stme = &sStage[wid][ln * STG];
    const int binbase = (ln >> 4) * 4;
    int bins_[DEPTHN];

    for (int d = 0; d < DEPTHN; ++d) {
        // per-row hmax (tree)
        float m01 = fmaxf(fabsf(h[0]), fabsf(h[1]));
        float m23 = fmaxf(fabsf(h[2]), fabsf(h[3]));
        float m45 = fmaxf(fabsf(h[4]), fabsf(h[5]));
        float m67 = fmaxf(fabsf(h[6]), fabsf(h[7]));
        float m89 = fmaxf(fabsf(h[8]), fabsf(h[9]));
        float mab = fmaxf(fabsf(h[10]), fabsf(h[11]));
        float mcd = fmaxf(fabsf(h[12]), fabsf(h[13]));
        float mef = fmaxf(fabsf(h[14]), fabsf(h[15]));
        float hmax = fmaxf(fmaxf(fmaxf(m01, m23), fmaxf(m45, m67)),
                           fmaxf(fmaxf(m89, mab), fmaxf(mcd, mef)));
        const float EPS_DUEL = 6e-4f * hmax + 1e-5f;
        const float EPS_FULL = 1.2e-3f * hmax + 2e-5f;

        // ---- bf16 2-term split; dwords [hi pairs(8) | lo pairs(8)] ----
        int dw[16];
#pragma unroll
        for (int i = 0; i < 8; ++i) {
            unsigned a  = bf16_rne(h[2 * i]);
            unsigned b  = bf16_rne(h[2 * i + 1]);
            unsigned la = bf16_rne(h[2 * i]     - bf16_to_f(a));
            unsigned lb = bf16_rne(h[2 * i + 1] - bf16_to_f(b));
            dw[i]     = (int)(a  | (b  << 16));
            dw[8 + i] = (int)(la | (lb << 16));
        }
        {
            i32x4 s0 = {dw[0], dw[1], dw[2], dw[3]};
            i32x4 s1 = {dw[4], dw[5], dw[6], dw[7]};
            i32x4 s2 = {dw[8], dw[9], dw[10], dw[11]};
            i32x4 s3 = {dw[12], dw[13], dw[14], dw[15]};
            *reinterpret_cast<i32x4*>(&stme[0])  = s0;
            *reinterpret_cast<i32x4*>(&stme[4])  = s1;
            *reinterpret_cast<i32x4*>(&stme[8])  = s2;
            *reinterpret_cast<i32x4*>(&stme[12]) = s3;
        }

        // ---- B-frags (h): rowgroup g, lane ln: row (ln&15)+16g, kgrp ln>>4 ----
        bf16x8 bfr[4];
#pragma unroll
        for (int g = 0; g < 4; ++g) {
            const i32x4* p = reinterpret_cast<const i32x4*>(
                &sStage[wid][((ln & 15) + 16 * g) * STG + (ln >> 4) * 4]);
            bfr[g] = __builtin_bit_cast(bf16x8, *p);
        }

        // stuffed top-3 per rowgroup (bin idx rides in low 8 mantissa bits)
        float p10 = -INFINITY, p20 = -INFINITY, p30 = -INFINITY;
        float p11 = -INFINITY, p21 = -INFINITY, p31 = -INFINITY;
        float p12 = -INFINITY, p22 = -INFINITY, p32 = -INFINITY;
        float p13 = -INFINITY, p23 = -INFINITY, p33 = -INFINITY;

#define SINS(M1, M2, M3, V, IB)                                            \
        {                                                                  \
            unsigned sb_ = (__builtin_bit_cast(unsigned, (V)) &            \
                            0xFFFFFF00u) | (unsigned)(IB);                 \
            float sv_ = __builtin_bit_cast(float, sb_);                    \
            M3 = fmaxf(M3, fminf(M2, sv_));                                \
            M2 = __builtin_amdgcn_fmed3f(M1, M2, sv_);                     \
            M1 = fmaxf(M1, sv_);                                           \
        }

        for (int bt = 0; bt < 16; ++bt) {
            i32x4 a0i = *reinterpret_cast<const i32x4*>(&sA[bt][ln][0]);
            i32x4 a1i = *reinterpret_cast<const i32x4*>(&sA[bt][ln ^ 32][0]);
            bf16x8 a0 = __builtin_bit_cast(bf16x8, a0i);
            bf16x8 a1 = __builtin_bit_cast(bf16x8, a1i);
            f32x4 bias4 = *reinterpret_cast<const f32x4*>(&sBias[16 * bt + binbase]);
            const int ib0 = (bt << 4) | (binbase + 0);
            const int ib1 = (bt << 4) | (binbase + 1);
            const int ib2 = (bt << 4) | (binbase + 2);
            const int ib3 = (bt << 4) | (binbase + 3);
#pragma unroll
            for (int g = 0; g < 4; ++g) {
                f32x4 acc = bias4;
                acc = __builtin_amdgcn_mfma_f32_16x16x32_bf16(a0, bfr[g], acc, 0, 0, 0);
                acc = __builtin_amdgcn_mfma_f32_16x16x32_bf16(a1, bfr[g], acc, 0, 0, 0);
                if (g == 0) {
                    SINS(p10, p20, p30, acc[0], ib0);
                    SINS(p10, p20, p30, acc[1], ib1);
                    SINS(p10, p20, p30, acc[2], ib2);
                    SINS(p10, p20, p30, acc[3], ib3);
                } else if (g == 1) {
                    SINS(p11, p21, p31, acc[0], ib0);
                    SINS(p11, p21, p31, acc[1], ib1);
                    SINS(p11, p21, p31, acc[2], ib2);
                    SINS(p11, p21, p31, acc[3], ib3);
                } else if (g == 2) {
                    SINS(p12, p22, p32, acc[0], ib0);
                    SINS(p12, p22, p32, acc[1], ib1);
                    SINS(p12, p22, p32, acc[2], ib2);
                    SINS(p12, p22, p32, acc[3], ib3);
                } else {
                    SINS(p13, p23, p33, acc[0], ib0);
                    SINS(p13, p23, p33, acc[1], ib1);
                    SINS(p13, p23, p33, acc[2], ib2);
                    SINS(p13, p23, p33, acc[3], ib3);
                }
            }
        }
#undef SINS

        // ---- merge across bin-holder lanes (xor16, xor32); keep own group ----
        float kmx = -INFINITY, ksec = -INFINITY, kt3 = -INFINITY;
#define MERGE_KEEP(M1, M2, M3, G)                                          \
        {                                                                  \
            float m1_ = M1, m2_ = M2, m3_ = M3;                            \
            _Pragma("unroll")                                              \
            for (int s = 16; s <= 32; s <<= 1) {                           \
                float q1 = __shfl_xor(m1_, s);                             \
                float q2 = __shfl_xor(m2_, s);                             \
                float q3 = __shfl_xor(m3_, s);                             \
                float nm1 = fmaxf(m1_, q1);                                \
                float nm2 = fmaxf(fminf(m1_, q1), fmaxf(m2_, q2));         \
                float nm3 = fmaxf(fmaxf(fminf(m2_, q1), fminf(m1_, q2)),   \
                                  fmaxf(m3_, q3));                         \
                m1_ = nm1; m2_ = nm2; m3_ = nm3;                           \
            }                                                              \
            bool own = ((ln >> 4) == (G));                                 \
            kmx = own ? m1_ : kmx;                                         \
            ksec = own ? m2_ : ksec;                                       \
            kt3 = own ? m3_ : kt3;                                         \
        }
        MERGE_KEEP(p10, p20, p30, 0)
        MERGE_KEEP(p11, p21, p31, 1)
        MERGE_KEEP(p12, p22, p32, 2)
        MERGE_KEEP(p13, p23, p33, 3)
#undef MERGE_KEEP

        int kgb = (int)(__builtin_bit_cast(unsigned, kmx) & 0xFFu);
        int ki2 = (int)(__builtin_bit_cast(unsigned, ksec) & 0xFFu);

        // ---- certified resolution (full-exact first: looser threshold) ----
        int bi;
        if (kmx - kt3 <= EPS_FULL) {
            // full exact no-FMA argmax (rare)
            float bb2 = -INFINITY;
            int bj = 0;
            for (int p = 0; p < NB / 2; ++p) {
                const v2f* wr = &WP[p * H];
                float a0 = 0.0f, a1 = 0.0f;
#pragma unroll
                for (int k = 0; k < H; ++k) {
                    v2f w = wr[k];
                    a0 = a0 + h[k] * w.x;
                    a1 = a1 + h[k] * w.y;
                }
                a0 = a0 + b_out[2 * p];
                a1 = a1 + b_out[2 * p + 1];
                if (a0 > bb2) { bb2 = a0; bj = 2 * p; }
                if (a1 > bb2) { bb2 = a1; bj = 2 * p + 1; }
            }
            bi = bj;
        } else if (kmx - ksec <= EPS_DUEL) {
            // exact 2-bin duel, first-index ties (sound: no sec/t3 swap here)
            int lo  = kgb < ki2 ? kgb : ki2;
            int hi2 = kgb < ki2 ? ki2 : kgb;
            float El = 0.0f, Eh = 0.0f;
            {
                const float* wr = ws + (lo >> 1) * 32 + (lo & 1);
#pragma unroll
                for (int k = 0; k < H; ++k) El = El + h[k] * wr[2 * k];
                El = El + b_out[lo];
            }
            {
                const float* wr = ws + (hi2 >> 1) * 32 + (hi2 & 1);
#pragma unroll
                for (int k = 0; k < H; ++k) Eh = Eh + h[k] * wr[2 * k];
                Eh = Eh + b_out[hi2];
            }
            bi = (Eh > El) ? hi2 : lo;
        } else {
            bi = kgb;
        }
        bins_[d] = bi;

        // ---- h = h + embed[bi] : EXACT (global gather, cached) ----
        {
            const float4* e = reinterpret_cast<const float4*>(embed + bi * H);
#pragma unroll
            for (int q4 = 0; q4 < 4; ++q4) {
                float4 ev = e[q4];
                h[q4 * 4 + 0] = h[q4 * 4 + 0] + ev.x;
                h[q4 * 4 + 1] = h[q4 * 4 + 1] + ev.y;
                h[q4 * 4 + 2] = h[q4 * 4 + 2] + ev.z;
                h[q4 * 4 + 3] = h[q4 * 4 + 3] + ev.w;
            }
        }

        // ---- z = h @ W_mlp + b_mlp ; silu : EXACT no-FMA + np-exp ----
        float hn[H];
#pragma unroll
        for (int i = 0; i < H; ++i) {
            const float* wr = &WM[i * H];
            float acc = 0.0f;
#pragma unroll
            for (int k = 0; k < H; ++k) acc = acc + h[k] * wr[k];
            acc = acc + b_mlp[i];
            float e = np_expf(-acc);
            float s = 1.0f / (1.0f + e);
            hn[i] = acc * s;
        }
#pragma unroll
        for (int i = 0; i < H; ++i) h[i] = hn[i];
    }

    // ---- write all bins once: 2x int4, coalesced ----
    int* o = out + (size_t)row * DEPTHN;
    *reinterpret_cast<int4*>(o)     = make_int4(bins_[0], bins_[1], bins_[2], bins_[3]);
    *reinterpret_cast<int4*>(o + 4) = make_int4(bins_[4], bins_[5], bins_[6], bins_[7]);
}

extern "C" void kernel_launch(void* const* d_in, const int* in_sizes, int n_in,
                              void* d_out, int out_size, void* d_ws, size_t ws_size,
                              hipStream_t stream) {
    const float* x     = (const float*)d_in[0];
    const float* W_in  = (const float*)d_in[1];
    const float* b_in  = (const float*)d_in[2];
    const float* embed = (const float*)d_in[3];
    const float* W_mlp = (const float*)d_in[4];
    const float* b_mlp = (const float*)d_in[5];
    const float* W_out = (const float*)d_in[6];
    const float* b_out = (const float*)d_in[7];
    int* out  = (int*)d_out;
    float* ws = (float*)d_ws;          // needs (4096+256)*4 = 17.4 KB

    addrnet_prep_kernel<<<1, 256, 0, stream>>>(W_out, W_mlp, ws);

    dim3 grid(BATCH / BLOCK);          // 2048 blocks, 8192 waves
    dim3 block(BLOCK);
    addrnet_r20_kernel<<<grid, block, 0, stream>>>(x, W_in, b_in, embed,
                                                   b_mlp, b_out, W_out, ws, out);
}

// Round 21
// 616.696 us; speedup vs baseline: 1.9797x; 1.9786x over previous
//
#include <hip/hip_runtime.h>
#include <math.h>

// AddrNet eval forward: B=524288, D_MODEL=128, HID=16, N_BINS=256, DEPTH=8.
// Round 21: R18 (PASSING, 618us) with ONE mapping change: BLOCK=512.
//  - sA (16 KB W-frags) now shared by 8 waves instead of 4; LDS total
//    16384 + 8*4352(stage,STG=17) + 1024(bias) = 52224 -> 3 blocks/CU
//    = 24 waves/CU (was 16) -> +50% occupancy cap for latency hiding.
//  - STG=17 (R15-proven conflict-free odd stride); stage via scalar dword
//    writes/reads (b128 needs 16B alignment which 17-stride lacks).
//  - __launch_bounds__(512,4): 64-VGPR cap (validated model cap=256/arg),
//    required for 6 waves/SIMD; R18's live set is 56 -> no spill.
// Everything else bit-identical to R18: MFMA bf16-2-term screen, 9-op INS
// tracker, EPS2 certification, exact no-FMA h-trajectory (R4 contract),
// np-Cephes exp. R19/R20's stuffed tracker measured 2x slower - reverted.

constexpr int BATCH  = 524288;
constexpr int DM     = 128;
constexpr int H      = 16;
constexpr int NB     = 256;
constexpr int DEPTHN = 8;

constexpr int BLOCK = 512;
constexpr int NWAVE = BLOCK / 64;
constexpr int STG   = 17;          // odd stride: conflict-free scalar stage

typedef float v2f    __attribute__((ext_vector_type(2)));
typedef float f32x4  __attribute__((ext_vector_type(4)));
typedef int   i32x4  __attribute__((ext_vector_type(4)));
typedef short bf16x8 __attribute__((ext_vector_type(8)));

__device__ __forceinline__ unsigned bf16_rne(float f) {
    unsigned u = __builtin_bit_cast(unsigned, f);
    return (u + 0x7fffu + ((u >> 16) & 1u)) >> 16;
}
__device__ __forceinline__ float bf16_to_f(unsigned b) {
    return __builtin_bit_cast(float, b << 16);
}

__device__ __forceinline__ float np_expf(float x) {
    // numpy SIMD f32 exp replica (Cephes). Verified R4 contract — do not touch.
    const float LOG2E = 1.442695040888963407f;
    const float C1    = 0.693359375f;
    const float C2    = -2.12194440e-4f;
    float q = rintf(x * LOG2E);
    float r = __builtin_fmaf(q, -C1, x);
    r = __builtin_fmaf(q, -C2, r);
    float p = 1.9875691500E-4f;
    p = __builtin_fmaf(p, r, 1.3981999507E-3f);
    p = __builtin_fmaf(p, r, 8.3334519073E-3f);
    p = __builtin_fmaf(p, r, 4.1665795894E-2f);
    p = __builtin_fmaf(p, r, 1.6666665459E-1f);
    p = __builtin_fmaf(p, r, 5.0000001201E-1f);
    p = __builtin_fmaf(p, r * r, r);
    p = p + 1.0f;
    if (x > 88.72283935546875f)      return INFINITY;
    if (x < -103.97208404541015625f) return 0.0f;
    return ldexpf(p, (int)q);
}

// ---- prep: exact-path weight layouts in d_ws (same as R14-R18).
//   ws[p*32 + k*2 + hh] = W_out[k][2p+hh]   p in [0,128)
//   ws[4096 + i*16 + k] = W_mlp[k][i]
__global__ void addrnet_prep_kernel(const float* __restrict__ W_out,
                                    const float* __restrict__ W_mlp,
                                    float* __restrict__ ws) {
    int t = threadIdx.x;
    for (int i = t; i < NB * H; i += 256) {
        int p = i >> 5, r = i & 31;
        int k = r >> 1, hh = r & 1;
        ws[i] = W_out[k * NB + (2 * p + hh)];
    }
    {
        int ii = t >> 4, k = t & 15;
        ws[NB * H + ii * H + k] = W_mlp[k * H + ii];
    }
}

__global__ __launch_bounds__(BLOCK, 4) void addrnet_r21_kernel(
    const float* __restrict__ x,      // [B,128]
    const float* __restrict__ W_in,   // [128,16]
    const float* __restrict__ b_in,   // [16]
    const float* __restrict__ embed,  // [256,16]
    const float* __restrict__ b_mlp,  // [16]
    const float* __restrict__ b_out,  // [256]
    const float* __restrict__ W_out,  // [16,256] (A-frag build)
    const float* __restrict__ ws,     // exact-path layouts
    int* __restrict__ out)            // [B,8] int32
{
#pragma clang fp contract(off)
    __shared__ __align__(16) int   sA[16][64][4];           // 16 KB (shared x8 waves)
    __shared__ __align__(16) int   sStage[NWAVE][64 * STG]; // 34816 B
    __shared__ __align__(16) float sBias[NB];               //  1 KB
    // total 52224 B -> 3 blocks/CU -> 24 waves/CU

    const int tid = threadIdx.x;
    const int ln  = tid & 63;
    const int wid = tid >> 6;

    // ---- build A-fragments (variant0), verified in R15-R18 ----
    for (int slot = tid; slot < 16 * 64; slot += BLOCK) {
        int bt = slot >> 6, l = slot & 63;
        int m  = 16 * bt + (l & 15);
        int k0 = (l >> 4) * 8;
        for (int j = 0; j < 4; ++j) {
            unsigned e2[2];
            for (int e = 0; e < 2; ++e) {
                int k  = k0 + 2 * j + e;
                int kk = k & 15;
                float w = W_out[kk * NB + m];
                unsigned whi = bf16_rne(w);
                unsigned wlo = bf16_rne(w - bf16_to_f(whi));
                e2[e] = (k < 16) ? whi : wlo;
            }
            sA[bt][l][j] = (int)(e2[0] | (e2[1] << 16));
        }
    }
    if (tid < NB) sBias[tid] = b_out[tid];
    __syncthreads();

    const float* WM = ws + NB * H;                       // WmlpT[i][k]
    const v2f*   WP = reinterpret_cast<const v2f*>(ws);  // exact pair layout

    const int row = blockIdx.x * BLOCK + tid;

    // ---- h = x @ W_in + b_in : EXACT no-FMA, k ascending, bias after ----
    float h[H];
#pragma unroll
    for (int j = 0; j < H; ++j) h[j] = 0.0f;
    const float4* xr = reinterpret_cast<const float4*>(x + (size_t)row * DM);
    for (int k4 = 0; k4 < DM / 4; ++k4) {
        float4 v = xr[k4];
        const float* w0 = &W_in[(k4 * 4 + 0) * H];
        const float* w1 = &W_in[(k4 * 4 + 1) * H];
        const float* w2 = &W_in[(k4 * 4 + 2) * H];
        const float* w3 = &W_in[(k4 * 4 + 3) * H];
#pragma unroll
        for (int j = 0; j < H; ++j) {
            float a = h[j];
            a = a + v.x * w0[j];
            a = a + v.y * w1[j];
            a = a + v.z * w2[j];
            a = a + v.w * w3[j];
            h[j] = a;
        }
    }
#pragma unroll
    for (int j = 0; j < H; ++j) h[j] = h[j] + b_in[j];

    int* o = out + (size_t)row * DEPTHN;
    int* stme = &sStage[wid][ln * STG];
    const int binbase = (ln >> 4) * 4;

    for (int d = 0; d < DEPTHN; ++d) {
        // hmax (tree)
        float m01 = fmaxf(fabsf(h[0]), fabsf(h[1]));
        float m23 = fmaxf(fabsf(h[2]), fabsf(h[3]));
        float m45 = fmaxf(fabsf(h[4]), fabsf(h[5]));
        float m67 = fmaxf(fabsf(h[6]), fabsf(h[7]));
        float m89 = fmaxf(fabsf(h[8]), fabsf(h[9]));
        float mab = fmaxf(fabsf(h[10]), fabsf(h[11]));
        float mcd = fmaxf(fabsf(h[12]), fabsf(h[13]));
        float mef = fmaxf(fabsf(h[14]), fabsf(h[15]));
        float hmax = fmaxf(fmaxf(fmaxf(m01, m23), fmaxf(m45, m67)),
                           fmaxf(fmaxf(m89, mab), fmaxf(mcd, mef)));
        const float EPS2 = 6e-4f * hmax + 1e-5f;

        // ---- bf16 2-term split; dwords [hi pairs(8) | lo pairs(8)] ----
        int dw[16];
#pragma unroll
        for (int i = 0; i < 8; ++i) {
            unsigned a  = bf16_rne(h[2 * i]);
            unsigned b  = bf16_rne(h[2 * i + 1]);
            unsigned la = bf16_rne(h[2 * i]     - bf16_to_f(a));
            unsigned lb = bf16_rne(h[2 * i + 1] - bf16_to_f(b));
            dw[i]     = (int)(a  | (b  << 16));
            dw[8 + i] = (int)(la | (lb << 16));
        }
#pragma unroll
        for (int i = 0; i < 16; ++i) stme[i] = dw[i];   // scalar, stride-17 safe

        // ---- B-frags (h): rowgroup g, lane ln: row (ln&15)+16g, kgrp ln>>4 ----
        bf16x8 bfr[4];
#pragma unroll
        for (int g = 0; g < 4; ++g) {
            const int* p = &sStage[wid][((ln & 15) + 16 * g) * STG + (ln >> 4) * 4];
            i32x4 v = {p[0], p[1], p[2], p[3]};
            bfr[g] = __builtin_bit_cast(bf16x8, v);
        }

        // running tuples per rowgroup
        float mx0 = -INFINITY, sec0 = -INFINITY, t30 = -INFINITY; int gb0 = 0, i20 = 0;
        float mx1 = -INFINITY, sec1 = -INFINITY, t31 = -INFINITY; int gb1 = 0, i21 = 0;
        float mx2 = -INFINITY, sec2 = -INFINITY, t32 = -INFINITY; int gb2 = 0, i22 = 0;
        float mx3 = -INFINITY, sec3 = -INFINITY, t33 = -INFINITY; int gb3 = 0, i23 = 0;

        // 9-op insert (R18-proven):
        //   t3' = max(t3, min(sec, v)); idx updates by cmp;
        //   sec' = med3(mx, sec, v);    mx' = max(mx, v)
#define INS(MX, GB, SEC, I2, T3, V, BIN)                                   \
        {                                                                  \
            float v_ = (V); int b_ = (BIN);                                \
            T3 = fmaxf(T3, fminf(SEC, v_));                                \
            bool c1 = v_ > MX;                                             \
            bool c2 = v_ > SEC;                                            \
            I2 = c1 ? GB : (c2 ? b_ : I2);                                 \
            GB = c1 ? b_ : GB;                                             \
            SEC = __builtin_amdgcn_fmed3f(MX, SEC, v_);                    \
            MX = fmaxf(MX, v_);                                            \
        }

        for (int bt = 0; bt < 16; ++bt) {
            i32x4 a0i = *reinterpret_cast<const i32x4*>(&sA[bt][ln][0]);
            i32x4 a1i = *reinterpret_cast<const i32x4*>(&sA[bt][ln ^ 32][0]);
            bf16x8 a0 = __builtin_bit_cast(bf16x8, a0i);
            bf16x8 a1 = __builtin_bit_cast(bf16x8, a1i);
            f32x4 bias4 = *reinterpret_cast<const f32x4*>(&sBias[16 * bt + binbase]);
            int bin0 = 16 * bt + binbase;
#pragma unroll
            for (int g = 0; g < 4; ++g) {
                f32x4 acc = bias4;
                acc = __builtin_amdgcn_mfma_f32_16x16x32_bf16(a0, bfr[g], acc, 0, 0, 0);
                acc = __builtin_amdgcn_mfma_f32_16x16x32_bf16(a1, bfr[g], acc, 0, 0, 0);
                if (g == 0) {
                    INS(mx0, gb0, sec0, i20, t30, acc[0], bin0 + 0);
                    INS(mx0, gb0, sec0, i20, t30, acc[1], bin0 + 1);
                    INS(mx0, gb0, sec0, i20, t30, acc[2], bin0 + 2);
                    INS(mx0, gb0, sec0, i20, t30, acc[3], bin0 + 3);
                } else if (g == 1) {
                    INS(mx1, gb1, sec1, i21, t31, acc[0], bin0 + 0);
                    INS(mx1, gb1, sec1, i21, t31, acc[1], bin0 + 1);
                    INS(mx1, gb1, sec1, i21, t31, acc[2], bin0 + 2);
                    INS(mx1, gb1, sec1, i21, t31, acc[3], bin0 + 3);
                } else if (g == 2) {
                    INS(mx2, gb2, sec2, i22, t32, acc[0], bin0 + 0);
                    INS(mx2, gb2, sec2, i22, t32, acc[1], bin0 + 1);
                    INS(mx2, gb2, sec2, i22, t32, acc[2], bin0 + 2);
                    INS(mx2, gb2, sec2, i22, t32, acc[3], bin0 + 3);
                } else {
                    INS(mx3, gb3, sec3, i23, t33, acc[0], bin0 + 0);
                    INS(mx3, gb3, sec3, i23, t33, acc[1], bin0 + 1);
                    INS(mx3, gb3, sec3, i23, t33, acc[2], bin0 + 2);
                    INS(mx3, gb3, sec3, i23, t33, acc[3], bin0 + 3);
                }
            }
        }
#undef INS

        // ---- merge 4 bin-holder lanes (xor 16, 32) per rowgroup; keep own ----
        float kmx = -INFINITY, ksec = -INFINITY, kt3 = -INFINITY;
        int kgb = 0, ki2 = 0;
#define MERGE_KEEP(MX, GB, SEC, I2, T3, G)                                 \
        {                                                                  \
            float mx_ = MX, sec_ = SEC, t3_ = T3; int gb_ = GB, i2_ = I2;  \
            _Pragma("unroll")                                              \
            for (int s = 16; s <= 32; s <<= 1) {                           \
                float pmx = __shfl_xor(mx_, s);                            \
                int   pgb = __shfl_xor(gb_, s);                            \
                float pse = __shfl_xor(sec_, s);                           \
                int   pi2 = __shfl_xor(i2_, s);                            \
                float pt3 = __shfl_xor(t3_, s);                            \
                bool t  = pmx > mx_;                                       \
                float nmx = t ? pmx : mx_;  int ngb = t ? pgb : gb_;       \
                float lmx = t ? mx_ : pmx;  int lgb = t ? gb_ : pgb;       \
                float wse = t ? pse : sec_; int wsi = t ? pi2 : i2_;       \
                bool u  = lmx > wse;                                       \
                float nse = u ? lmx : wse;  int ni2 = u ? lgb : wsi;       \
                float c3  = u ? wse : lmx;                                 \
                float lse = t ? sec_ : pse;                                \
                float nt3 = fmaxf(fmaxf(c3, lse), fmaxf(t3_, pt3));        \
                mx_ = nmx; gb_ = ngb; sec_ = nse; i2_ = ni2; t3_ = nt3;    \
            }                                                              \
            bool own = ((ln >> 4) == (G));                                 \
            kmx = own ? mx_ : kmx;   kgb = own ? gb_ : kgb;                \
            ksec = own ? sec_ : ksec; ki2 = own ? i2_ : ki2;               \
            kt3 = own ? t3_ : kt3;                                         \
        }
        MERGE_KEEP(mx0, gb0, sec0, i20, t30, 0)
        MERGE_KEEP(mx1, gb1, sec1, i21, t31, 1)
        MERGE_KEEP(mx2, gb2, sec2, i22, t32, 2)
        MERGE_KEEP(mx3, gb3, sec3, i23, t33, 3)
#undef MERGE_KEEP

        // ---- certified resolution ----
        int bi;
        if (kmx - kt3 <= EPS2) {
            // full exact no-FMA argmax (rare)
            float bb2 = -INFINITY;
            int bj = 0;
            for (int p = 0; p < NB / 2; ++p) {
                const v2f* wr = &WP[p * H];
                float a0 = 0.0f, a1 = 0.0f;
#pragma unroll
                for (int k = 0; k < H; ++k) {
                    v2f w = wr[k];
                    a0 = a0 + h[k] * w.x;
                    a1 = a1 + h[k] * w.y;
                }
                a0 = a0 + b_out[2 * p];
                a1 = a1 + b_out[2 * p + 1];
                if (a0 > bb2) { bb2 = a0; bj = 2 * p; }
                if (a1 > bb2) { bb2 = a1; bj = 2 * p + 1; }
            }
            bi = bj;
        } else if (kmx - ksec <= EPS2) {
            // exact 2-bin duel, first-index ties
            int lo  = kgb < ki2 ? kgb : ki2;
            int hi2 = kgb < ki2 ? ki2 : kgb;
            float El = 0.0f, Eh = 0.0f;
            {
                const float* wr = ws + (lo >> 1) * 32 + (lo & 1);
#pragma unroll
                for (int k = 0; k < H; ++k) El = El + h[k] * wr[2 * k];
                El = El + b_out[lo];
            }
            {
                const float* wr = ws + (hi2 >> 1) * 32 + (hi2 & 1);
#pragma unroll
                for (int k = 0; k < H; ++k) Eh = Eh + h[k] * wr[2 * k];
                Eh = Eh + b_out[hi2];
            }
            bi = (Eh > El) ? hi2 : lo;
        } else {
            bi = kgb;
        }
        o[d] = bi;

        // ---- h = h + embed[bi] : EXACT (global gather, cached) ----
        {
            const float4* e = reinterpret_cast<const float4*>(embed + bi * H);
#pragma unroll
            for (int q4 = 0; q4 < 4; ++q4) {
                float4 ev = e[q4];
                h[q4 * 4 + 0] = h[q4 * 4 + 0] + ev.x;
                h[q4 * 4 + 1] = h[q4 * 4 + 1] + ev.y;
                h[q4 * 4 + 2] = h[q4 * 4 + 2] + ev.z;
                h[q4 * 4 + 3] = h[q4 * 4 + 3] + ev.w;
            }
        }

        // ---- z = h @ W_mlp + b_mlp ; silu : EXACT no-FMA + np-exp ----
        float hn[H];
#pragma unroll
        for (int i = 0; i < H; ++i) {
            const float* wr = &WM[i * H];
            float acc = 0.0f;
#pragma unroll
            for (int k = 0; k < H; ++k) acc = acc + h[k] * wr[k];
            acc = acc + b_mlp[i];
            float e = np_expf(-acc);
            float s = 1.0f / (1.0f + e);
            hn[i] = acc * s;
        }
#pragma unroll
        for (int i = 0; i < H; ++i) h[i] = hn[i];
    }
}

extern "C" void kernel_launch(void* const* d_in, const int* in_sizes, int n_in,
                              void* d_out, int out_size, void* d_ws, size_t ws_size,
                              hipStream_t stream) {
    const float* x     = (const float*)d_in[0];
    const float* W_in  = (const float*)d_in[1];
    const float* b_in  = (const float*)d_in[2];
    const float* embed = (const float*)d_in[3];
    const float* W_mlp = (const float*)d_in[4];
    const float* b_mlp = (const float*)d_in[5];
    const float* W_out = (const float*)d_in[6];
    const float* b_out = (const float*)d_in[7];
    int* out  = (int*)d_out;
    float* ws = (float*)d_ws;          // needs (4096+256)*4 = 17.4 KB

    addrnet_prep_kernel<<<1, 256, 0, stream>>>(W_out, W_mlp, ws);

    dim3 grid(BATCH / BLOCK);          // 1024 blocks, 8192 waves
    dim3 block(BLOCK);
    addrnet_r21_kernel<<<grid, block, 0, stream>>>(x, W_in, b_in, embed,
                                                   b_mlp, b_out, W_out, ws, out);
}